// Round 5
// baseline (13048.026 us; speedup 1.0000x reference)
//
#include <hip/hip_runtime.h>
#include <stdint.h>

// ---------------------------------------------------------------------------
// Seq2Seq (V=10000, E=256, H=512, B=64, T=128).
// Output rows are one-hot: only argmax(logits + gumbel) matters (bit-exact
// JAX threefry, partitionable XOR variant — verified R3/R4, absmax 0.0).
// R5: recurrence -> MFMA split-bf16 step kernel, no LDS/no barriers,
//     h carried in bf16-split A-fragment layout between steps.
// ---------------------------------------------------------------------------

typedef short bf16x8 __attribute__((ext_vector_type(8)));
typedef float f32x4 __attribute__((ext_vector_type(4)));

__device__ __forceinline__ void threefry2x32(uint32_t k0, uint32_t k1,
                                             uint32_t x0, uint32_t x1,
                                             uint32_t& o0, uint32_t& o1)
{
  const uint32_t k2 = k0 ^ k1 ^ 0x1BD11BDAu;
  x0 += k0; x1 += k1;
#define TF_R(r) x0 += x1; x1 = (x1 << r) | (x1 >> (32 - r)); x1 ^= x0;
  TF_R(13) TF_R(15) TF_R(26) TF_R(6)
  x0 += k1; x1 += k2 + 1u;
  TF_R(17) TF_R(29) TF_R(16) TF_R(24)
  x0 += k2; x1 += k0 + 2u;
  TF_R(13) TF_R(15) TF_R(26) TF_R(6)
  x0 += k0; x1 += k1 + 3u;
  TF_R(17) TF_R(29) TF_R(16) TF_R(24)
  x0 += k1; x1 += k2 + 4u;
  TF_R(13) TF_R(15) TF_R(26) TF_R(6)
  x0 += k2; x1 += k0 + 5u;
#undef TF_R
  o0 = x0; o1 = x1;
}

// jax.random.uniform bits, partitionable scheme, 32-bit = o0 ^ o1 (verified)
__device__ __forceinline__ float jax_uniform(uint32_t seed, uint32_t i)
{
  uint32_t o0, o1;
  threefry2x32(0u, seed, 0u, i, o0, o1);
  const uint32_t bits = o0 ^ o1;
  return __uint_as_float(0x3F800000u | (bits >> 9)) - 1.0f;
}

__device__ __forceinline__ ushort f2bf(float x)   // fp32 -> bf16 bits, RNE
{
  const uint32_t u = __float_as_uint(x);
  const uint32_t r = u + 0x7FFFu + ((u >> 16) & 1u);
  return (ushort)(r >> 16);
}
__device__ __forceinline__ float bf2f(ushort b)
{
  return __uint_as_float(((uint32_t)b) << 16);
}

__device__ __forceinline__ unsigned long long packkey(float f, int n)
{
  uint32_t u = __float_as_uint(f);
  u = (u & 0x80000000u) ? ~u : (u | 0x80000000u);   // order-preserving map
  return ((unsigned long long)u << 32) | (uint32_t)(0x7FFFFFFF - n);
}

// ---------------------------------------------------------------------------
__global__ __launch_bounds__(256)
void split_kernel(const float* __restrict__ src, ushort* __restrict__ hi,
                  ushort* __restrict__ lo, int n)
{
  const int i = blockIdx.x * 256 + threadIdx.x;
  if (i < n) {
    const float v = src[i];
    const ushort h = f2bf(v);
    hi[i] = h;
    lo[i] = f2bf(v - bf2f(h));
  }
}

// ---------------------------------------------------------------------------
// seq [t][k=512][b=64] fp32  ->  T hi/lo [t*64+b][k] bf16 (row-major M x K)
// ---------------------------------------------------------------------------
__global__ __launch_bounds__(256)
void transpose_split_kernel(const float* __restrict__ seq,
                            ushort* __restrict__ Thi, ushort* __restrict__ Tlo)
{
  __shared__ float tile[128][65];
  const int t = blockIdx.x >> 2;
  const int kc = blockIdx.x & 3;
  const int tid = threadIdx.x;
  const float* sbase = seq + (size_t)t * 32768 + (size_t)kc * 128 * 64;
#pragma unroll
  for (int it = 0; it < 32; ++it) {
    const int idx = it * 256 + tid;
    tile[idx >> 6][idx & 63] = sbase[idx];
  }
  __syncthreads();
#pragma unroll
  for (int it = 0; it < 32; ++it) {
    const int idx = it * 256 + tid;
    const int b = idx >> 7, k = idx & 127;
    const float v = tile[k][b];
    const size_t o = ((size_t)t * 64 + b) * 512 + kc * 128 + k;
    const ushort h = f2bf(v);
    Thi[o] = h;
    Tlo[o] = f2bf(v - bf2f(h));
  }
}

// ---------------------------------------------------------------------------
// Split-bf16 MFMA GEMM (verified R4). 128x128 block tile, 4 waves.
// FUSED=0: store Xg packed [t][n][b] (+bias).  FUSED=1: gumbel-argmax.
// ---------------------------------------------------------------------------
template <int GATHER, int FUSED>
__global__ __launch_bounds__(256)
void gemm_split(const ushort* __restrict__ Ahi, const ushort* __restrict__ Alo,
                const int* __restrict__ ids,
                const ushort* __restrict__ Whi, const ushort* __restrict__ Wlo,
                const float* __restrict__ bias, float* __restrict__ Xg,
                const int* __restrict__ mask, const int* __restrict__ idxmap,
                unsigned long long* __restrict__ keys,
                int M, int N, int K)
{
  const int tid = threadIdx.x;
  const int wid = tid >> 6, lane = tid & 63;
  const int lm = lane & 15, quad = lane >> 4;
  const int m0 = blockIdx.x * 128 + (wid >> 1) * 64;
  const int n0 = blockIdx.y * 128 + (wid & 1) * 64;
  const int koff = quad * 8;

  size_t offA[4];
#pragma unroll
  for (int mi = 0; mi < 4; ++mi) {
    int m = m0 + mi * 16 + lm;
    int mc = m < M ? m : (M - 1);
    if (GATHER) {
      const int tok = ids[(mc & 63) * 128 + (mc >> 6)];
      offA[mi] = (size_t)tok * K;
    } else {
      offA[mi] = (size_t)mc * K;
    }
  }
  size_t offB[4];
#pragma unroll
  for (int ni = 0; ni < 4; ++ni) {
    int n = n0 + ni * 16 + lm;
    int nc = n < N ? n : (N - 1);
    offB[ni] = (size_t)nc * K;
  }

  f32x4 acc[4][4];
#pragma unroll
  for (int mi = 0; mi < 4; ++mi)
#pragma unroll
    for (int ni = 0; ni < 4; ++ni) acc[mi][ni] = (f32x4){0.f, 0.f, 0.f, 0.f};

  for (int k0 = 0; k0 < K; k0 += 32) {
    bf16x8 ah[4], al[4];
#pragma unroll
    for (int mi = 0; mi < 4; ++mi) {
      ah[mi] = *(const bf16x8*)(Ahi + offA[mi] + k0 + koff);
      al[mi] = *(const bf16x8*)(Alo + offA[mi] + k0 + koff);
    }
#pragma unroll
    for (int ni = 0; ni < 4; ++ni) {
      const bf16x8 bh = *(const bf16x8*)(Whi + offB[ni] + k0 + koff);
      const bf16x8 bl = *(const bf16x8*)(Wlo + offB[ni] + k0 + koff);
#pragma unroll
      for (int mi = 0; mi < 4; ++mi) {
        acc[mi][ni] = __builtin_amdgcn_mfma_f32_16x16x32_bf16(ah[mi], bl, acc[mi][ni], 0, 0, 0);
        acc[mi][ni] = __builtin_amdgcn_mfma_f32_16x16x32_bf16(al[mi], bh, acc[mi][ni], 0, 0, 0);
        acc[mi][ni] = __builtin_amdgcn_mfma_f32_16x16x32_bf16(ah[mi], bh, acc[mi][ni], 0, 0, 0);
      }
    }
  }

  float bv[4];
#pragma unroll
  for (int ni = 0; ni < 4; ++ni) {
    int n = n0 + ni * 16 + lm;
    bv[ni] = bias[n < N ? n : (N - 1)];
  }

  if (FUSED == 0) {
#pragma unroll
    for (int mi = 0; mi < 4; ++mi) {
#pragma unroll
      for (int i = 0; i < 4; ++i) {
        const int m = m0 + mi * 16 + quad * 4 + i;
        if (m >= M) continue;
        const int t = m >> 6, b = m & 63;
        float* base = Xg + (size_t)t * 131072 + b;
#pragma unroll
        for (int ni = 0; ni < 4; ++ni) {
          const int n = n0 + ni * 16 + lm;
          base[(size_t)n * 64] = acc[mi][ni][i] + bv[ni];
        }
      }
    }
  } else {
#pragma unroll
    for (int mi = 0; mi < 4; ++mi) {
#pragma unroll
      for (int i = 0; i < 4; ++i) {
        const int m = m0 + mi * 16 + quad * 4 + i;
        if (m >= M) continue;
        const int j = m >> 6, b = m & 63;
        const int outrow = b * 128 + j + 1;
        if (mask[outrow] == 0) continue;
        const int r = idxmap[outrow];
        const uint32_t base7 = (uint32_t)(r * 64 + b) * 10000u;
        float best = -3.0e38f;
        int bestn = 0;
#pragma unroll
        for (int ni = 0; ni < 4; ++ni) {
          const int n = n0 + ni * 16 + lm;
          if (n < N) {
            const float u7 = jax_uniform(7u, base7 + (uint32_t)n);
            const float g = -logf(-logf(u7 + 1e-20f) + 1e-20f);
            const float z = acc[mi][ni][i] + bv[ni] + g;
            if (z > best) { best = z; bestn = n; }
          }
        }
        unsigned long long key = packkey(best, bestn);
#pragma unroll
        for (int s = 1; s < 16; s <<= 1) {
          const unsigned long long o = __shfl_xor(key, s, 64);
          if (o > key) key = o;
        }
        if (lm == 0) atomicMax(keys + outrow, key);
      }
    }
  }
}

// ---------------------------------------------------------------------------
// R5 LSTM step via MFMA. 32 blocks x 256 thr; wave mi handles batches
// [mi*16, mi*16+16), block handles units [U0, U0+16) x 4 gates.
// h carried as bf16 split in A-fragment layout hs[b][k=u] (512-stride).
// Whh pre-split bf16 hi/lo row-major [2048][512]. No LDS, no barriers.
// gates = h @ Whh^T via 3-pass split MFMA; nonlinearity fused in-lane.
// ---------------------------------------------------------------------------
__global__ __launch_bounds__(256)
void lstm_step_mfma(const float* __restrict__ Xg,
                    const ushort* __restrict__ hHi, const ushort* __restrict__ hLo,
                    const ushort* __restrict__ WHi, const ushort* __restrict__ WLo,
                    float* __restrict__ cstate, float* __restrict__ hout,
                    ushort* __restrict__ oHi, ushort* __restrict__ oLo)
{
  const int tid = threadIdx.x;
  const int mi = tid >> 6;
  const int lane = tid & 63;
  const int lm = lane & 15, quad = lane >> 4;
  const int u = blockIdx.x * 16 + lm;
  const int koff = quad * 8;

  const ushort* aHi = hHi + (size_t)(mi * 16 + lm) * 512 + koff;
  const ushort* aLo = hLo + (size_t)(mi * 16 + lm) * 512 + koff;
  const ushort* bH[4];
  const ushort* bL[4];
#pragma unroll
  for (int g = 0; g < 4; ++g) {
    const size_t o = (size_t)(g * 512 + u) * 512 + koff;
    bH[g] = WHi + o;
    bL[g] = WLo + o;
  }

  f32x4 acc[4];
#pragma unroll
  for (int g = 0; g < 4; ++g) acc[g] = (f32x4){0.f, 0.f, 0.f, 0.f};

#pragma unroll 4
  for (int k0 = 0; k0 < 512; k0 += 32) {
    const bf16x8 ah = *(const bf16x8*)(aHi + k0);
    const bf16x8 al = *(const bf16x8*)(aLo + k0);
#pragma unroll
    for (int g = 0; g < 4; ++g) {
      const bf16x8 bh = *(const bf16x8*)(bH[g] + k0);
      const bf16x8 bl = *(const bf16x8*)(bL[g] + k0);
      acc[g] = __builtin_amdgcn_mfma_f32_16x16x32_bf16(ah, bl, acc[g], 0, 0, 0);
      acc[g] = __builtin_amdgcn_mfma_f32_16x16x32_bf16(al, bh, acc[g], 0, 0, 0);
      acc[g] = __builtin_amdgcn_mfma_f32_16x16x32_bf16(ah, bh, acc[g], 0, 0, 0);
    }
  }

  // epilogue: lane owns unit u, batches b0..b0+3
  const int b0 = mi * 16 + quad * 4;
  const float4 xi = *(const float4*)(Xg + (size_t)(0 * 512 + u) * 64 + b0);
  const float4 xf = *(const float4*)(Xg + (size_t)(1 * 512 + u) * 64 + b0);
  const float4 xg = *(const float4*)(Xg + (size_t)(2 * 512 + u) * 64 + b0);
  const float4 xo = *(const float4*)(Xg + (size_t)(3 * 512 + u) * 64 + b0);
  float4 c4 = *(float4*)(cstate + (size_t)u * 64 + b0);

  float4 h4;
#pragma unroll
  for (int r = 0; r < 4; ++r) {
    const float zi = acc[0][r] + ((const float*)&xi)[r];
    const float zf = acc[1][r] + ((const float*)&xf)[r];
    const float zg = acc[2][r] + ((const float*)&xg)[r];
    const float zo = acc[3][r] + ((const float*)&xo)[r];
    const float I = 1.0f / (1.0f + expf(-zi));
    const float F = 1.0f / (1.0f + expf(-zf));
    const float G = tanhf(zg);
    const float O = 1.0f / (1.0f + expf(-zo));
    const float cn = F * ((float*)&c4)[r] + I * G;
    ((float*)&c4)[r] = cn;
    ((float*)&h4)[r] = O * tanhf(cn);
  }
  *(float4*)(cstate + (size_t)u * 64 + b0) = c4;
  *(float4*)(hout + (size_t)u * 64 + b0) = h4;
#pragma unroll
  for (int r = 0; r < 4; ++r) {
    const float hv = ((const float*)&h4)[r];
    const ushort hh = f2bf(hv);
    oHi[(size_t)(b0 + r) * 512 + u] = hh;
    oLo[(size_t)(b0 + r) * 512 + u] = f2bf(hv - bf2f(hh));
  }
}

// ---------------------------------------------------------------------------
__global__ void maskscan_kernel(const int* __restrict__ mask,
                                int* __restrict__ idxmap)
{
  const int b = threadIdx.x;   // 64 threads
  int run = 0;
  for (int t = 0; t < 128; ++t) {
    idxmap[b * 128 + t] = run;
    run += mask[b * 128 + t];
  }
}

__global__ __launch_bounds__(256)
void t0_kernel(const int* __restrict__ mask, unsigned long long* __restrict__ keys)
{
  const int b = blockIdx.x;
  const int row = b * 128;
  if (mask[row] == 0) return;
  const int tid = threadIdx.x;
  const uint32_t base = (uint32_t)b * 10000u;
  float best = -3.0e38f;
  int bestn = 0;
  for (int v = tid; v < 10000; v += 256) {
    const float u42 = jax_uniform(42u, base + (uint32_t)v);
    const float u7 = jax_uniform(7u, base + (uint32_t)v);
    const float g = -logf(-logf(u7 + 1e-20f) + 1e-20f);
    const float z = u42 + g;
    if (z > best) { best = z; bestn = v; }
  }
  __shared__ unsigned long long sk[256];
  sk[tid] = packkey(best, bestn);
  __syncthreads();
  for (int s = 128; s > 0; s >>= 1) {
    if (tid < s) { if (sk[tid + s] > sk[tid]) sk[tid] = sk[tid + s]; }
    __syncthreads();
  }
  if (tid == 0) keys[row] = sk[0];
}

__global__ __launch_bounds__(256)
void finalize_kernel(const unsigned long long* __restrict__ keys,
                     const int* __restrict__ mask,
                     const int* __restrict__ input_ids,
                     int* __restrict__ tokens)
{
  const int row = blockIdx.x * 256 + threadIdx.x;
  if (row < 8192) {
    tokens[row] = mask[row] ? (int)(0x7FFFFFFFu - (uint32_t)(keys[row] & 0xFFFFFFFFu))
                            : input_ids[row];
  }
}

__global__ __launch_bounds__(256)
void onehot_kernel(const int* __restrict__ tokens, float* __restrict__ out)
{
  const int row = blockIdx.x;
  const int tok = tokens[row];
  float4* orow = (float4*)(out + (size_t)row * 10000);
  for (int q = threadIdx.x; q < 2500; q += 256) {
    float4 v = make_float4(0.f, 0.f, 0.f, 0.f);
    const int v0 = q << 2;
    const unsigned d = (unsigned)(tok - v0);
    if (d < 4u) ((float*)&v)[d] = 1.0f;
    orow[q] = v;
  }
}

__global__ __launch_bounds__(256)
void zero_kernel(float* __restrict__ p, int n)
{
  const int i = blockIdx.x * 256 + threadIdx.x;
  if (i < n) p[i] = 0.f;
}

// ---------------------------------------------------------------------------
extern "C" void kernel_launch(void* const* d_in, const int* in_sizes, int n_in,
                              void* d_out, int out_size, void* d_ws, size_t ws_size,
                              hipStream_t stream)
{
  const int*   input_ids = (const int*)d_in[0];
  const int*   mask      = (const int*)d_in[1];
  const float* enc_embed = (const float*)d_in[3];
  const float* enc_Wih0  = (const float*)d_in[4];
  const float* enc_Whh0  = (const float*)d_in[5];
  const float* enc_b0    = (const float*)d_in[6];
  const float* enc_Wih1  = (const float*)d_in[7];
  const float* enc_Whh1  = (const float*)d_in[8];
  const float* enc_b1    = (const float*)d_in[9];
  const float* dec_embed = (const float*)d_in[10];
  const float* dec_Wih0  = (const float*)d_in[11];
  const float* dec_Whh0  = (const float*)d_in[12];
  const float* dec_b0    = (const float*)d_in[13];
  const float* dec_Wih1  = (const float*)d_in[14];
  const float* dec_Whh1  = (const float*)d_in[15];
  const float* dec_b1    = (const float*)d_in[16];
  const float* dec_Wout  = (const float*)d_in[17];
  const float* dec_bout  = (const float*)d_in[18];

  // ---- d_out doubles as scratch (327.68 MB); all dead before onehot ----
  char* O = (char*)d_out;
  float*  Xg    = (float*)(O + 0);                    // 8192*2048 f32
  ushort* sThi  = (ushort*)(O + 67108864);
  ushort* sTlo  = (ushort*)(O + 75497472);
  ushort* eEh   = (ushort*)(O + 83886080);
  ushort* eEl   = (ushort*)(O + 89006080);
  ushort* dEh   = (ushort*)(O + 94126080);
  ushort* dEl   = (ushort*)(O + 99246080);
  ushort* eW0h  = (ushort*)(O + 104366080);
  ushort* eW0l  = (ushort*)(O + 105414656);
  ushort* eW1h  = (ushort*)(O + 106463232);
  ushort* eW1l  = (ushort*)(O + 108560384);
  ushort* dW0h  = (ushort*)(O + 110657536);
  ushort* dW0l  = (ushort*)(O + 111706112);
  ushort* dW1h  = (ushort*)(O + 112754688);
  ushort* dW1l  = (ushort*)(O + 114851840);
  ushort* Woh   = (ushort*)(O + 116948992);
  ushort* Wol   = (ushort*)(O + 127188992);
  unsigned long long* keys = (unsigned long long*)(O + 137428992);
  int*    idxmap = (int*)(O + 137494528);
  // Whh splits (each 2,097,152 B)
  ushort* eH0h = (ushort*)(O + 137527296);
  ushort* eH0l = (ushort*)(O + 139624448);
  ushort* eH1h = (ushort*)(O + 141721600);
  ushort* eH1l = (ushort*)(O + 143818752);
  ushort* dH0h = (ushort*)(O + 145915904);
  ushort* dH0l = (ushort*)(O + 148013056);
  ushort* dH1h = (ushort*)(O + 150110208);
  ushort* dH1l = (ushort*)(O + 152207360);
  // h-split state buffers, 65,536 B each, contiguous (zeroed in one shot)
  ushort* hsAhi = (ushort*)(O + 154304512);
  ushort* hsAlo = (ushort*)(O + 154370048);
  ushort* hsBhi = (ushort*)(O + 154435584);
  ushort* hsBlo = (ushort*)(O + 154501120);
  ushort* hsChi = (ushort*)(O + 154566656);
  ushort* hsClo = (ushort*)(O + 154632192);
  ushort* hsDhi = (ushort*)(O + 154697728);
  ushort* hsDlo = (ushort*)(O + 154763264);

  // ---- workspace ----
  float* seqA = (float*)d_ws;                         // 128*32768 f32
  float* zbuf = seqA + (size_t)128 * 32768;           // (unused, layout keep)
  float* cA   = zbuf + 32768;
  float* cB   = cA + 32768;
  float* hp0  = cB + 32768;                           // dummy hout (enc L1)
  float* hp1  = hp0 + 32768;
  int* tokens = (int*)(hp1 + 32768);

  zero_kernel<<<256, 256, 0, stream>>>(cA, 2 * 32768);           // cA, cB
  zero_kernel<<<512, 256, 0, stream>>>((float*)hsAhi, 131072);   // all hs bufs
  zero_kernel<<<64, 256, 0, stream>>>((float*)keys, 16384);
  maskscan_kernel<<<1, 64, 0, stream>>>(mask, idxmap);

  // ---- one-shot precision splits ----
  split_kernel<<<10000, 256, 0, stream>>>(enc_embed, eEh, eEl, 2560000);
  split_kernel<<<10000, 256, 0, stream>>>(dec_embed, dEh, dEl, 2560000);
  split_kernel<<<2048, 256, 0, stream>>>(enc_Wih0, eW0h, eW0l, 524288);
  split_kernel<<<4096, 256, 0, stream>>>(enc_Wih1, eW1h, eW1l, 1048576);
  split_kernel<<<2048, 256, 0, stream>>>(dec_Wih0, dW0h, dW0l, 524288);
  split_kernel<<<4096, 256, 0, stream>>>(dec_Wih1, dW1h, dW1l, 1048576);
  split_kernel<<<20000, 256, 0, stream>>>(dec_Wout, Woh, Wol, 5120000);
  split_kernel<<<4096, 256, 0, stream>>>(enc_Whh0, eH0h, eH0l, 1048576);
  split_kernel<<<4096, 256, 0, stream>>>(enc_Whh1, eH1h, eH1l, 1048576);
  split_kernel<<<4096, 256, 0, stream>>>(dec_Whh0, dH0h, dH0l, 1048576);
  split_kernel<<<4096, 256, 0, stream>>>(dec_Whh1, dH1h, dH1l, 1048576);

  // ---- encoder layer 0: h-split chain A<->B, final lands in A (128 steps) --
  gemm_split<1, 0><<<dim3(64, 16), 256, 0, stream>>>(
      eEh, eEl, input_ids, eW0h, eW0l, enc_b0, Xg,
      nullptr, nullptr, nullptr, 8192, 2048, 256);
  for (int t = 0; t < 128; ++t) {
    const ushort* ih = (t & 1) ? hsBhi : hsAhi;
    const ushort* il = (t & 1) ? hsBlo : hsAlo;
    ushort* oh = (t & 1) ? hsAhi : hsBhi;
    ushort* ol = (t & 1) ? hsAlo : hsBlo;
    lstm_step_mfma<<<32, 256, 0, stream>>>(
        Xg + (size_t)t * 131072, ih, il, eH0h, eH0l, cA,
        seqA + (size_t)t * 32768, oh, ol);
  }

  // ---- encoder layer 1: chain C<->D, final lands in C ----
  transpose_split_kernel<<<512, 256, 0, stream>>>(seqA, sThi, sTlo);
  gemm_split<0, 0><<<dim3(64, 16), 256, 0, stream>>>(
      sThi, sTlo, nullptr, eW1h, eW1l, enc_b1, Xg,
      nullptr, nullptr, nullptr, 8192, 2048, 512);
  for (int t = 0; t < 128; ++t) {
    const ushort* ih = (t & 1) ? hsDhi : hsChi;
    const ushort* il = (t & 1) ? hsDlo : hsClo;
    ushort* oh = (t & 1) ? hsChi : hsDhi;
    ushort* ol = (t & 1) ? hsClo : hsDlo;
    lstm_step_mfma<<<32, 256, 0, stream>>>(
        Xg + (size_t)t * 131072, ih, il, eH1h, eH1l, cB, hp0, oh, ol);
  }

  // ---- decoder layer 0: init h = enc L0 final (in hsA), c = cA; 127 steps --
  gemm_split<1, 0><<<dim3(64, 16), 256, 0, stream>>>(
      dEh, dEl, input_ids, dW0h, dW0l, dec_b0, Xg,
      nullptr, nullptr, nullptr, 8128, 2048, 256);
  for (int j = 0; j < 127; ++j) {
    const ushort* ih = (j & 1) ? hsBhi : hsAhi;
    const ushort* il = (j & 1) ? hsBlo : hsAlo;
    ushort* oh = (j & 1) ? hsAhi : hsBhi;
    ushort* ol = (j & 1) ? hsAlo : hsBlo;
    lstm_step_mfma<<<32, 256, 0, stream>>>(
        Xg + (size_t)j * 131072, ih, il, dH0h, dH0l, cA,
        seqA + (size_t)j * 32768, oh, ol);
  }

  // ---- decoder layer 1: init h = enc L1 final (in hsC), c = cB ----
  transpose_split_kernel<<<508, 256, 0, stream>>>(seqA, sThi, sTlo);
  gemm_split<0, 0><<<dim3(64, 16), 256, 0, stream>>>(
      sThi, sTlo, nullptr, dW1h, dW1l, dec_b1, Xg,
      nullptr, nullptr, nullptr, 8128, 2048, 512);
  for (int j = 0; j < 127; ++j) {
    const ushort* ih = (j & 1) ? hsDhi : hsChi;
    const ushort* il = (j & 1) ? hsDlo : hsClo;
    ushort* oh = (j & 1) ? hsChi : hsDhi;
    ushort* ol = (j & 1) ? hsClo : hsDlo;
    lstm_step_mfma<<<32, 256, 0, stream>>>(
        Xg + (size_t)j * 131072, ih, il, dH1h, dH1l, cB,
        seqA + (size_t)j * 32768, oh, ol);
  }

  // ---- fused logits + gumbel-argmax (no logits materialization) ----
  transpose_split_kernel<<<508, 256, 0, stream>>>(seqA, sThi, sTlo);
  gemm_split<0, 1><<<dim3(64, 79), 256, 0, stream>>>(
      sThi, sTlo, nullptr, Woh, Wol, dec_bout, nullptr,
      mask, idxmap, keys, 8128, 10000, 512);
  t0_kernel<<<64, 256, 0, stream>>>(mask, keys);

  // ---- tokens -> one-hot output ----
  finalize_kernel<<<32, 256, 0, stream>>>(keys, mask, input_ids, tokens);
  onehot_kernel<<<8192, 256, 0, stream>>>(tokens, (float*)d_out);
}